// Round 5
// baseline (355.282 us; speedup 1.0000x reference)
//
#include <hip/hip_runtime.h>
#include <hip/hip_bf16.h>
#include <math.h>

// GatedAttention pipeline, all-bf16 MFMA GEMMs (threshold 1.04e-1 is bf16-scale).
// R10: gemm256 per-wave read/MFMA INTERLEAVE. R9 post-mortem: pinning regions
//      without reordering kept [all 24 reads] before [all 64 MFMA]; with the
//      tile barrier aligning all 8 waves, the CU alternated LDS-storm (matrix
//      idle, ~2300cy) and MFMA-burst (LDS idle, ~2480cy) = 5634cy/tile serial.
//      Fix: program-order interleave, sched_barrier(0)-pinned:
//        [af0+bq0 12 reads]|[bq1 4]|[MFMA q0 x16]|[af1 8]|[MFMA q1]|[q2]|[q3]
//      Compiler emits counted lgkmcnt (q0 waits only its 12; q1 allows af1's 8
//      outstanding; q2's lgkm(0) hides under q1's ~310cy). Only q0's reads are
//      exposed post-barrier; the other 12 reads + next-tile GLD LDS-writes run
//      under the 2480cy MFMA window. Runtime skeleton unchanged from R8/R9
//      (8 GLD at tile top, counted vmcnt(8), ONE barrier/tile, final lgkm(0)).
//
//  prep_all: cast input -> cat[:, :1024]; cast memory -> memory_bf16;
//            copy memory -> out tail; transpose W_in1/W_mem1/W_in2/memory
//  G1: input_dot = relu(cat[:, :1024] @ W1T^T + b1)          (M=16384,N=1024,K=1024)  [256^2]
//  G2: memory_dot = relu(memory_bf16 @ WmT^T + bm)           (M=4096, N=1024,K=1024)  [128^2]
//  G3: att = input_dot @ memory_dot^T / 32   [batched z=8]   (M=2048, N=512, K=1024)  [128^2]
//  softmax rows (mask) fp32 att -> compact bf16 wAtt (=input_dot buffer)
//  G4: output_one = wAtt @ memT^T -> cat[:, 1024:2048]       (M=2048, N=1024,K=512)   [256^2]
//  G5: out = gate(cat @ W2T^T + b2)                          (M=16384,N=1024,K=2048)  [256^2]

using bf16_t = __hip_bfloat16;
typedef __attribute__((ext_vector_type(8))) __bf16 bf16x8;
typedef __attribute__((ext_vector_type(4))) float f32x4;

#define BM 128
#define BN 128
#define BK 64

#define EPI_RELU_BIAS_BF16 0
#define EPI_SCALE_F32      1
#define EPI_BF16           2
#define EPI_GATE_BIAS_F32  3

#define SB() __builtin_amdgcn_sched_barrier(0)

// direct global->LDS DMA, 16B per lane; LDS dest = wave-uniform base + lane*16
#define GLD16(gp, lp)                                                        \
    __builtin_amdgcn_global_load_lds(                                        \
        (const __attribute__((address_space(1))) void*)(gp),                 \
        (__attribute__((address_space(3))) void*)(lp), 16, 0, 0)

__device__ __forceinline__ void epi_store(int MODE, void* Cg, const float* bias,
                                          long idx, int col, float v, float scale)
{
    if (MODE == EPI_RELU_BIAS_BF16) {
        float t = v + bias[col];
        t = t > 0.f ? t : 0.f;
        ((bf16_t*)Cg)[idx] = __float2bfloat16(t);
    } else if (MODE == EPI_SCALE_F32) {
        ((float*)Cg)[idx] = v * scale;
    } else if (MODE == EPI_BF16) {
        ((bf16_t*)Cg)[idx] = __float2bfloat16(v);
    } else { // EPI_GATE_BIAS_F32: sigmoid(p)*tanh(p) via one exp
        float p = v + bias[col];
        p = fminf(fmaxf(p, -30.f), 30.f);
        const float u  = __expf(-p);
        const float u2 = u * u;
        ((float*)Cg)[idx] = (1.f - u2) / ((1.f + u) * (1.f + u2));
    }
}

// ---------------------------------------------------------------------------
// 256x256 tile, BK=64, 8 waves (2M x 4N), 128 KiB LDS double buffer.
// One barrier + one counted vmcnt per K-tile; per-wave interleaved
// read/MFMA pipeline inside the tile (sched_barrier-pinned ORDER).
// C = A (M x K, row-major, LDA) @ B^T (B is N x K row-major, LDB), batched z.
// Requires M%256==0, N%256==0, K%64==0, (gridDim.x*gridDim.y)%8==0.
// ---------------------------------------------------------------------------
template<int MODE, int K, int LDA, int LDB, int LDC>
__global__ __launch_bounds__(512)
void gemm256(const bf16_t* __restrict__ Ag, const bf16_t* __restrict__ Bg,
             void* __restrict__ Cg, const float* __restrict__ bias,
             long sA, long sB, long sC, float scale)
{
    // [buf][A/B][256 rows x 64 cols]  = 128 KiB
    __shared__ alignas(16) bf16_t smem[2][2][256 * 64];

    const int z = blockIdx.z;
    const bf16_t* A = Ag + (long)z * sA;
    const bf16_t* B = Bg + (long)z * sB;

    const int tid  = threadIdx.x;
    const int lane = tid & 63;
    const int wave = tid >> 6;          // 0..7
    const int wm   = wave >> 2;         // 0..1  -> M offset wm*128
    const int wn   = wave & 3;          // 0..3  -> N offset wn*64
    const int quad = lane >> 4;         // 0..3
    const int l16  = lane & 15;

    // bijective XCD chunk swizzle (nwg % 8 == 0 for all launches here),
    // then column-major decomposition -> each XCD works one B column panel.
    const int gx = gridDim.x, gy = gridDim.y;
    const int nwg = gx * gy;
    const int lin = blockIdx.y * gx + blockIdx.x;
    const int swz = (lin & 7) * (nwg >> 3) + (lin >> 3);
    const int colBlk = swz / gy;
    const int rowBlk = swz - colBlk * gy;
    const int rowBase = rowBlk * 256;
    const int colBase = colBlk * 256;

    f32x4 acc[8][4];
    #pragma unroll
    for (int i = 0; i < 8; ++i)
        #pragma unroll
        for (int j = 0; j < 4; ++j)
            acc[i][j] = (f32x4){0.f, 0.f, 0.f, 0.f};

    // staging: wave w covers tile rows [w*32, w*32+32), 4 rounds of 8 rows.
    // lane i -> row_local i>>3, LDS chunk i&7; global chunk = (i&7)^(row&7).
    const int srow   = lane >> 3;                 // 0..7
    const int gchunk = (lane & 7) ^ srow;
    const int scol   = gchunk * 8;
    const bf16_t* pA = A + (long)(rowBase + wave * 32 + srow) * LDA + scol;
    const bf16_t* pB = B + (long)(colBase + wave * 32 + srow) * LDB + scol;

    // fragment-read chunk selectors (unswizzled chunk ks*4+quad at row r,
    // stored at chunk (ks*4+quad)^(r&7); r&7 == l16&7 for all frag rows)
    const int cs0 = ((0 * 4 + quad) ^ (l16 & 7)) * 8;
    const int cs1 = ((1 * 4 + quad) ^ (l16 & 7)) * 8;

    constexpr int NT = K / 64;

    // prologue: stage K-tile 0 into buf 0 (8 global_load_lds / thread)
    #pragma unroll
    for (int j = 0; j < 4; ++j) {
        GLD16(pA + (long)(j * 8) * LDA, &smem[0][0][(wave * 32 + j * 8) * 64]);
        GLD16(pB + (long)(j * 8) * LDB, &smem[0][1][(wave * 32 + j * 8) * 64]);
    }
    pA += 64; pB += 64;

    #pragma unroll 1
    for (int t = 0; t < NT; ++t) {
        const int cur = t & 1;
        // issue next tile's 8 loads, then wait ONLY for this tile's 8.
        // buf[cur^1] is safe: all waves proved (via the previous barrier,
        // preceded by their lgkmcnt(0)) that their reads of it completed.
        if (t + 1 < NT) {
            #pragma unroll
            for (int j = 0; j < 4; ++j) {
                GLD16(pA + (long)(j * 8) * LDA, &smem[cur ^ 1][0][(wave * 32 + j * 8) * 64]);
                GLD16(pB + (long)(j * 8) * LDB, &smem[cur ^ 1][1][(wave * 32 + j * 8) * 64]);
            }
            pA += 64; pB += 64;
            asm volatile("s_waitcnt vmcnt(8)" ::: "memory");
        } else {
            asm volatile("s_waitcnt vmcnt(0)" ::: "memory");
        }
        asm volatile("s_barrier" ::: "memory");   // tile-t data visible to all

        const bf16_t* Ab = &smem[cur][0][0];
        const bf16_t* Bb = &smem[cur][1][0];

        bf16x8 af0[4][2], af1[4][2], bq0[2][2], bq1[2][2];

        // --- R1: af0 (8) + bq0 (4) --- the q0 MFMA front needs exactly these
        #pragma unroll
        for (int mi = 0; mi < 4; ++mi) {
            const int ro = (wm * 128 + mi * 16 + l16) * 64;
            af0[mi][0] = *(const bf16x8*)&Ab[ro + cs0];
            af0[mi][1] = *(const bf16x8*)&Ab[ro + cs1];
        }
        #pragma unroll
        for (int ni = 0; ni < 2; ++ni) {
            const int ro = (wn * 64 + ni * 16 + l16) * 64;
            bq0[ni][0] = *(const bf16x8*)&Bb[ro + cs0];
            bq0[ni][1] = *(const bf16x8*)&Bb[ro + cs1];
        }
        SB();
        // --- R2: bq1 (4) --- stays in flight across q0 (lgkmcnt(4) before q0)
        #pragma unroll
        for (int ni = 0; ni < 2; ++ni) {
            const int ro = (wn * 64 + 32 + ni * 16 + l16) * 64;
            bq1[ni][0] = *(const bf16x8*)&Bb[ro + cs0];
            bq1[ni][1] = *(const bf16x8*)&Bb[ro + cs1];
        }
        SB();
        // --- q0: af0 x bq0 (16 MFMA) ---
        __builtin_amdgcn_s_setprio(1);
        #pragma unroll
        for (int mi = 0; mi < 4; ++mi)
            #pragma unroll
            for (int ni = 0; ni < 2; ++ni) {
                acc[mi][ni] = __builtin_amdgcn_mfma_f32_16x16x32_bf16(
                    af0[mi][0], bq0[ni][0], acc[mi][ni], 0, 0, 0);
                acc[mi][ni] = __builtin_amdgcn_mfma_f32_16x16x32_bf16(
                    af0[mi][1], bq0[ni][1], acc[mi][ni], 0, 0, 0);
            }
        __builtin_amdgcn_s_setprio(0);
        SB();
        // --- R3: af1 (8) --- issued under q0's shadow in other waves; its
        // completion wait (lgkmcnt(0) before q2) hides under q1's MFMA window
        #pragma unroll
        for (int mi = 0; mi < 4; ++mi) {
            const int ro = (wm * 128 + 64 + mi * 16 + l16) * 64;
            af1[mi][0] = *(const bf16x8*)&Ab[ro + cs0];
            af1[mi][1] = *(const bf16x8*)&Ab[ro + cs1];
        }
        SB();
        // --- q1: af0 x bq1 ---
        __builtin_amdgcn_s_setprio(1);
        #pragma unroll
        for (int mi = 0; mi < 4; ++mi)
            #pragma unroll
            for (int ni = 0; ni < 2; ++ni) {
                acc[mi][2 + ni] = __builtin_amdgcn_mfma_f32_16x16x32_bf16(
                    af0[mi][0], bq1[ni][0], acc[mi][2 + ni], 0, 0, 0);
                acc[mi][2 + ni] = __builtin_amdgcn_mfma_f32_16x16x32_bf16(
                    af0[mi][1], bq1[ni][1], acc[mi][2 + ni], 0, 0, 0);
            }
        SB();
        // --- q2: af1 x bq0 ---
        #pragma unroll
        for (int mi = 0; mi < 4; ++mi)
            #pragma unroll
            for (int ni = 0; ni < 2; ++ni) {
                acc[4 + mi][ni] = __builtin_amdgcn_mfma_f32_16x16x32_bf16(
                    af1[mi][0], bq0[ni][0], acc[4 + mi][ni], 0, 0, 0);
                acc[4 + mi][ni] = __builtin_amdgcn_mfma_f32_16x16x32_bf16(
                    af1[mi][1], bq0[ni][1], acc[4 + mi][ni], 0, 0, 0);
            }
        SB();
        // --- q3: af1 x bq1 ---
        #pragma unroll
        for (int mi = 0; mi < 4; ++mi)
            #pragma unroll
            for (int ni = 0; ni < 2; ++ni) {
                acc[4 + mi][2 + ni] = __builtin_amdgcn_mfma_f32_16x16x32_bf16(
                    af1[mi][0], bq1[ni][0], acc[4 + mi][2 + ni], 0, 0, 0);
                acc[4 + mi][2 + ni] = __builtin_amdgcn_mfma_f32_16x16x32_bf16(
                    af1[mi][1], bq1[ni][1], acc[4 + mi][2 + ni], 0, 0, 0);
            }
        __builtin_amdgcn_s_setprio(0);

        // all 24 of this wave's ds_reads complete before it can reach the
        // next tile's barrier -> buf reuse there is race-free.
        asm volatile("s_waitcnt lgkmcnt(0)" ::: "memory");
        SB();
    }

    // epilogue: C/D layout col = lane&15, row = quad*4 + reg
    #pragma unroll
    for (int mi = 0; mi < 8; ++mi) {
        #pragma unroll
        for (int ni = 0; ni < 4; ++ni) {
            #pragma unroll
            for (int r = 0; r < 4; ++r) {
                const int row = rowBase + wm * 128 + mi * 16 + quad * 4 + r;
                const int col = colBase + wn * 64 + ni * 16 + l16;
                const long idx = (long)z * sC + (long)row * LDC + col;
                epi_store(MODE, Cg, bias, idx, col, acc[mi][ni][r], scale);
            }
        }
    }
}

// ---------------------------------------------------------------------------
// 128x128 tile kernel (R6 structure) -- kept for G2/G3 whose 256^2 grids
// would only fill 64-128 of the 256 CUs.
// ---------------------------------------------------------------------------
template<int MODE, int K, int LDA, int LDB, int LDC>
__global__ __launch_bounds__(256)
void gemm_bt(const bf16_t* __restrict__ Ag, const bf16_t* __restrict__ Bg,
             void* __restrict__ Cg, const float* __restrict__ bias,
             long sA, long sB, long sC, float scale)
{
    __shared__ alignas(16) bf16_t As[BM * BK];   // 16 KB
    __shared__ alignas(16) bf16_t Bs[BN * BK];   // 16 KB

    const int z = blockIdx.z;
    const bf16_t* A = Ag + (long)z * sA;
    const bf16_t* B = Bg + (long)z * sB;

    const int tid  = threadIdx.x;
    const int lane = tid & 63;
    const int wave = tid >> 6;
    const int wr   = (wave >> 1) * 64;   // wave row offset in 128x128 tile
    const int wc   = (wave & 1) * 64;    // wave col offset
    const int quad = lane >> 4;          // 0..3
    const int l16  = lane & 15;

    // XCD swizzle: column-major reinterpretation of the linear block ID
    const int bidLin = blockIdx.y * gridDim.x + blockIdx.x;
    const int colBlk = bidLin / gridDim.y;
    const int rowBlk = bidLin - colBlk * gridDim.y;
    const int rowBase = rowBlk * BM;
    const int colBase = colBlk * BN;

    f32x4 acc[4][4];
    #pragma unroll
    for (int i = 0; i < 4; ++i)
        #pragma unroll
        for (int j = 0; j < 4; ++j)
            acc[i][j] = (f32x4){0.f, 0.f, 0.f, 0.f};

    const int srow   = lane >> 3;                  // 0..7
    const int gchunk = (lane & 7) ^ srow;          // swizzled global chunk
    const int scol   = gchunk * 8;                 // element offset 0..56

    const bf16_t* pA = A + (long)(rowBase + wave * 32 + srow) * LDA + scol;
    const bf16_t* pB = B + (long)(colBase + wave * 32 + srow) * LDB + scol;
    bf16_t* lA = &As[(wave * 32) * BK];
    bf16_t* lB = &Bs[(wave * 32) * BK];

    const int csel0 = ((0 * 4 + quad) ^ (l16 & 7)) * 8;
    const int csel1 = ((1 * 4 + quad) ^ (l16 & 7)) * 8;

    #pragma unroll 1
    for (int k0 = 0; k0 < K; k0 += BK) {
        #pragma unroll
        for (int j = 0; j < 4; ++j) {
            GLD16(pA + (long)(j * 8) * LDA, lA + j * 8 * BK);
            GLD16(pB + (long)(j * 8) * LDB, lB + j * 8 * BK);
        }
        pA += BK; pB += BK;
        __syncthreads();   // drains vmcnt (global_load_lds)

        #pragma unroll
        for (int h = 0; h < 2; ++h) {
            const int cs = h ? csel1 : csel0;
            bf16x8 af[4], bfr[4];
            #pragma unroll
            for (int mi = 0; mi < 4; ++mi)
                af[mi] = *(const bf16x8*)(&As[(wr + mi * 16 + l16) * BK + cs]);
            #pragma unroll
            for (int ni = 0; ni < 4; ++ni)
                bfr[ni] = *(const bf16x8*)(&Bs[(wc + ni * 16 + l16) * BK + cs]);

            #pragma unroll
            for (int mi = 0; mi < 4; ++mi)
                #pragma unroll
                for (int ni = 0; ni < 4; ++ni)
                    acc[mi][ni] = __builtin_amdgcn_mfma_f32_16x16x32_bf16(
                        af[mi], bfr[ni], acc[mi][ni], 0, 0, 0);
        }
        __syncthreads();
    }

    #pragma unroll
    for (int mi = 0; mi < 4; ++mi) {
        #pragma unroll
        for (int ni = 0; ni < 4; ++ni) {
            #pragma unroll
            for (int r = 0; r < 4; ++r) {
                const int row = rowBase + wr + mi * 16 + quad * 4 + r;
                const int col = colBase + wc + ni * 16 + l16;
                const long idx = (long)z * sC + (long)row * LDC + col;
                epi_store(MODE, Cg, bias, idx, col, acc[mi][ni][r], scale);
            }
        }
    }
}

// fused prep: blocks [0,24576): cast input -> cat left half, cast memory -> memb,
//             copy memory -> out tail (float4 groups).
//             blocks [24576,32768): 32x32 transpose tiles for W1T/WmT/W2T/memT.
__global__ __launch_bounds__(256)
void prep_all(const float4* __restrict__ input, const float4* __restrict__ memory,
              const float* __restrict__ W_in1, const float* __restrict__ W_mem1,
              const float* __restrict__ W_in2,
              bf16_t* __restrict__ cat, bf16_t* __restrict__ memb,
              float4* __restrict__ outTail,
              bf16_t* __restrict__ W1T, bf16_t* __restrict__ WmT,
              bf16_t* __restrict__ W2T, bf16_t* __restrict__ memT)
{
    __shared__ float tile[32][33];
    const int bid = blockIdx.x;
    if (bid < 24576) {
        const long i = (long)bid * 256 + threadIdx.x;
        if (i < 4194304L) {               // input cast -> cat left half
            const float4 v = input[i];
            const long e = i << 2;
            const long row = e >> 10;
            const int  col = (int)(e & 1023);
            bf16_t* o = cat + row * 2048 + col;
            o[0] = __float2bfloat16(v.x);
            o[1] = __float2bfloat16(v.y);
            o[2] = __float2bfloat16(v.z);
            o[3] = __float2bfloat16(v.w);
        } else if (i < 5242880L) {        // memory cast (contiguous)
            const long j = i - 4194304L;
            const float4 v = memory[j];
            bf16_t* o = memb + (j << 2);
            o[0] = __float2bfloat16(v.x);
            o[1] = __float2bfloat16(v.y);
            o[2] = __float2bfloat16(v.z);
            o[3] = __float2bfloat16(v.w);
        } else {                          // memory passthrough -> out tail
            const long j = i - 5242880L;
            outTail[j] = memory[j];
        }
        return;
    }

    // transpose section: out[c][r] = bf16(in[r][c]), 32x32 tiles
    int local = bid - 24576;
    const float* in; bf16_t* out; int R, C, bx, by;
    if (local < 1024)      { in = W_in1;  out = W1T; R = 1024; C = 1024;
                             bx = local & 31; by = local >> 5; }
    else if (local < 2048) { local -= 1024; in = W_mem1; out = WmT; R = 1024; C = 1024;
                             bx = local & 31; by = local >> 5; }
    else if (local < 4096) { local -= 2048; in = W_in2;  out = W2T; R = 2048; C = 1024;
                             bx = local & 31; by = local >> 5; }
    else                   { local -= 4096;
                             const int zz = local >> 9;          // 0..7
                             const int r  = local & 511;
                             bx = r & 31; by = r >> 5;           // by 0..15
                             in  = (const float*)memory + (long)zz * 524288;
                             out = memT + (long)zz * 524288;
                             R = 512; C = 1024; }

    const int x = threadIdx.x & 31, y = threadIdx.x >> 5;   // y in 0..7
    const int c0 = bx * 32, r0 = by * 32;
    #pragma unroll
    for (int i = 0; i < 32; i += 8)
        tile[y + i][x] = in[(long)(r0 + y + i) * C + c0 + x];
    __syncthreads();
    #pragma unroll
    for (int i = 0; i < 32; i += 8)
        out[(long)(c0 + y + i) * R + r0 + x] = __float2bfloat16(tile[x][y + i]);
}

// one wave per row of 512; att fp32 in, compact bf16 weights out (row stride 512).
__global__ __launch_bounds__(256)
void softmax_rows(const float* __restrict__ att, const int* __restrict__ mask,
                  bf16_t* __restrict__ wAtt)
{
    const int lane = threadIdx.x & 63;
    const long row = (long)blockIdx.x * 4 + (threadIdx.x >> 6);
    const int n = (int)(row >> 11);          // 2048 rows per batch
    const float* base = att + row * 512;
    const int* mrow = mask + n * 512;

    float v[8];
    #pragma unroll
    for (int j = 0; j < 8; ++j) {
        const int idx = j * 64 + lane;
        const float x = base[idx];
        v[j] = mrow[idx] ? x : -1e30f;
    }
    float mx = v[0];
    #pragma unroll
    for (int j = 1; j < 8; ++j) mx = fmaxf(mx, v[j]);
    #pragma unroll
    for (int off = 32; off >= 1; off >>= 1) mx = fmaxf(mx, __shfl_xor(mx, off, 64));
    float s = 0.f;
    #pragma unroll
    for (int j = 0; j < 8; ++j) { v[j] = __expf(v[j] - mx); s += v[j]; }
    #pragma unroll
    for (int off = 32; off >= 1; off >>= 1) s += __shfl_xor(s, off, 64);
    const float inv = 1.0f / s;

    bf16_t* w = wAtt + row * 512;
    #pragma unroll
    for (int j = 0; j < 8; ++j)
        w[j * 64 + lane] = __float2bfloat16(v[j] * inv);
}

extern "C" void kernel_launch(void* const* d_in, const int* in_sizes, int n_in,
                              void* d_out, int out_size, void* d_ws, size_t ws_size,
                              hipStream_t stream)
{
    const float* input  = (const float*)d_in[0];   // 8 x 2048 x 1024
    const float* memory = (const float*)d_in[1];   // 8 x 512 x 1024
    const int*   mask   = (const int*)  d_in[2];   // 8 x 512
    const float* W_in1  = (const float*)d_in[3];   // 1024 x 1024
    const float* b_in1  = (const float*)d_in[4];
    const float* W_mem1 = (const float*)d_in[5];   // 1024 x 1024
    const float* b_mem1 = (const float*)d_in[6];
    const float* W_in2  = (const float*)d_in[7];   // 2048 x 1024
    const float* b_in2  = (const float*)d_in[8];
    float* out = (float*)d_out;                    // 16777216 gated + 4194304 memory

    char* ws = (char*)d_ws;
    bf16_t* cat         = (bf16_t*)(ws);                 // 16384 x 2048   (67108864 B)
    bf16_t* input_dot   = (bf16_t*)(ws + 67108864);      // 16384 x 1024   (33554432 B)
    bf16_t* memory_dot  = (bf16_t*)(ws + 100663296);     //  4096 x 1024   ( 8388608 B)
    bf16_t* memory_bf16 = (bf16_t*)(ws + 109051904);     //  4096 x 1024   ( 8388608 B)
    bf16_t* memT        = (bf16_t*)(ws + 117440512);     // 8 x 1024 x 512 ( 8388608 B)
    bf16_t* W1T         = (bf16_t*)(ws + 125829120);     // 1024 x 1024    ( 2097152 B)
    bf16_t* WmT         = (bf16_t*)(ws + 127926272);     // 1024 x 1024    ( 2097152 B)
    bf16_t* W2T         = (bf16_t*)(ws + 130023424);     // 1024 x 2048    ( 4194304 B)
    float*  att         = (float*)(ws + 134217728);      // 8 x 2048 x 512 (33554432 B) -> end 167772160
    bf16_t* wAtt        = input_dot;   // reclaimed after G3: compact bf16 softmax weights

    // fused prep (casts + passthrough + all transposes)
    prep_all<<<32768, 256, 0, stream>>>((const float4*)input, (const float4*)memory,
                                        W_in1, W_mem1, W_in2,
                                        cat, memory_bf16, (float4*)(out + 16777216L),
                                        W1T, WmT, W2T, memT);

    // G1: input_dot = relu(input @ W_in1 + b_in1)   [256^2, 256 blocks]
    gemm256<EPI_RELU_BIAS_BF16, 1024, 2048, 1024, 1024><<<dim3(4, 64, 1), 512, 0, stream>>>(
        cat, W1T, input_dot, b_in1, 0, 0, 0, 1.0f);
    // G2: memory_dot = relu(memory @ W_mem1 + b_mem1)   [128^2, 256 blocks]
    gemm_bt<EPI_RELU_BIAS_BF16, 1024, 1024, 1024, 1024><<<dim3(8, 32, 1), 256, 0, stream>>>(
        memory_bf16, WmT, memory_dot, b_mem1, 0, 0, 0, 1.0f);
    // G3: att = input_dot @ memory_dot^T / 32   (batched)   [128^2, 512 blocks]
    gemm_bt<EPI_SCALE_F32, 1024, 1024, 1024, 512><<<dim3(4, 16, 8), 256, 0, stream>>>(
        input_dot, memory_dot, att, nullptr,
        2048L * 1024, 512L * 1024, 2048L * 512, 0.03125f);
    // softmax: fp32 att -> compact bf16 wAtt (input_dot buffer is dead after G3)
    softmax_rows<<<4096, 256, 0, stream>>>(att, mask, wAtt);
    // G4: output_one = wAtt @ memT^T -> cat[:, 1024:2048]   [256^2, 256 blocks]
    gemm256<EPI_BF16, 512, 512, 512, 2048><<<dim3(4, 8, 8), 512, 0, stream>>>(
        wAtt, memT, cat + 1024, nullptr,
        2048L * 512, 1024L * 512, 2048L * 2048, 1.0f);
    // G5: out = sigmoid(pre) * tanh(pre), pre = cat @ W_in2 + b_in2   [256^2]
    gemm256<EPI_GATE_BIAS_F32, 2048, 2048, 2048, 1024><<<dim3(4, 64, 1), 512, 0, stream>>>(
        cat, W2T, out, b_in2, 0, 0, 0, 1.0f);
}

// Round 6
// 346.543 us; speedup vs baseline: 1.0252x; 1.0252x over previous
//
#include <hip/hip_runtime.h>
#include <hip/hip_bf16.h>
#include <math.h>

// GatedAttention pipeline, all-bf16 MFMA GEMMs (threshold 1.04e-1 is bf16-scale).
// R11: gemm256 ported to the verified 4-phase barrier-paired interleave (m201
//      style). R8-R10 post-mortem: any [24 reads]->[64 MFMA] order per wave
//      serializes the CU's two ~2500cy streams (LDS service 192KB reads +
//      64KB GLD writes ~2550cy; MFMA 2484cy) -> 5400cy/tile, MfmaUtil 38%.
//      Fix per tile (phases = C-quadrants, af cached over qn, bq over qm):
//       P1: af0+bq0 reads (kh0 group first -> counted lgkmcnt(6), kh0 MFMAs
//           start while kh1 reads fly) + 4 GLD; MFMA q00; barrier
//       P2: bq1(4) + af1(8 prefetch) + 2 GLD; MFMA q01 (needs bq1 only ->
//           lgkmcnt(8), af1 services under this MFMA); barrier
//       P3: 2 GLD; MFMA q10 (af1 landed); barrier
//       P4: MFMA q11 (0 reads); vmcnt(0) (stages had 1.5-3k cy); barrier
//      Per-phase ~6-12 read bursts stagger waves via LDS FIFO; LDS runs under
//      adjacent phases' MFMA; staging spread {4,2,2,0} GLD avoids the write
//      storm. Counted waits only (compiler-emitted, no asm lgkmcnt in loop).
//
//  prep_all: cast input -> cat[:, :1024]; cast memory -> memory_bf16;
//            copy memory -> out tail; transpose W_in1/W_mem1/W_in2/memory
//  G1: input_dot = relu(cat[:, :1024] @ W1T^T + b1)          (M=16384,N=1024,K=1024)  [256^2]
//  G2: memory_dot = relu(memory_bf16 @ WmT^T + bm)           (M=4096, N=1024,K=1024)  [128^2]
//  G3: att = input_dot @ memory_dot^T / 32   [batched z=8]   (M=2048, N=512, K=1024)  [128^2]
//  softmax rows (mask) fp32 att -> compact bf16 wAtt (=input_dot buffer)
//  G4: output_one = wAtt @ memT^T -> cat[:, 1024:2048]       (M=2048, N=1024,K=512)   [256^2]
//  G5: out = gate(cat @ W2T^T + b2)                          (M=16384,N=1024,K=2048)  [256^2]

using bf16_t = __hip_bfloat16;
typedef __attribute__((ext_vector_type(8))) __bf16 bf16x8;
typedef __attribute__((ext_vector_type(4))) float f32x4;

#define BM 128
#define BN 128
#define BK 64

#define EPI_RELU_BIAS_BF16 0
#define EPI_SCALE_F32      1
#define EPI_BF16           2
#define EPI_GATE_BIAS_F32  3

#define SB() __builtin_amdgcn_sched_barrier(0)

// direct global->LDS DMA, 16B per lane; LDS dest = wave-uniform base + lane*16
#define GLD16(gp, lp)                                                        \
    __builtin_amdgcn_global_load_lds(                                        \
        (const __attribute__((address_space(1))) void*)(gp),                 \
        (__attribute__((address_space(3))) void*)(lp), 16, 0, 0)

__device__ __forceinline__ void epi_store(int MODE, void* Cg, const float* bias,
                                          long idx, int col, float v, float scale)
{
    if (MODE == EPI_RELU_BIAS_BF16) {
        float t = v + bias[col];
        t = t > 0.f ? t : 0.f;
        ((bf16_t*)Cg)[idx] = __float2bfloat16(t);
    } else if (MODE == EPI_SCALE_F32) {
        ((float*)Cg)[idx] = v * scale;
    } else if (MODE == EPI_BF16) {
        ((bf16_t*)Cg)[idx] = __float2bfloat16(v);
    } else { // EPI_GATE_BIAS_F32: sigmoid(p)*tanh(p) via one exp
        float p = v + bias[col];
        p = fminf(fmaxf(p, -30.f), 30.f);
        const float u  = __expf(-p);
        const float u2 = u * u;
        ((float*)Cg)[idx] = (1.f - u2) / ((1.f + u) * (1.f + u2));
    }
}

// ---------------------------------------------------------------------------
// 256x256 tile, BK=64, 8 waves (2M x 4N), 128 KiB LDS double buffer.
// 4-phase barrier-paired interleave per K-tile; counted (compiler) lgkmcnt;
// staging spread {4,2,2,0} GLD per phase; per-wave vmcnt(0) at tile top.
// C = A (M x K, row-major, LDA) @ B^T (B is N x K row-major, LDB), batched z.
// Requires M%256==0, N%256==0, K%64==0, (gridDim.x*gridDim.y)%8==0.
// ---------------------------------------------------------------------------
template<int MODE, int K, int LDA, int LDB, int LDC>
__global__ __launch_bounds__(512)
void gemm256(const bf16_t* __restrict__ Ag, const bf16_t* __restrict__ Bg,
             void* __restrict__ Cg, const float* __restrict__ bias,
             long sA, long sB, long sC, float scale)
{
    // [buf][A/B][256 rows x 64 cols]  = 128 KiB
    __shared__ alignas(16) bf16_t smem[2][2][256 * 64];

    const int z = blockIdx.z;
    const bf16_t* A = Ag + (long)z * sA;
    const bf16_t* B = Bg + (long)z * sB;

    const int tid  = threadIdx.x;
    const int lane = tid & 63;
    const int wave = tid >> 6;          // 0..7
    const int wm   = wave >> 2;         // 0..1  -> M offset wm*128
    const int wn   = wave & 3;          // 0..3  -> N offset wn*64
    const int quad = lane >> 4;         // 0..3
    const int l16  = lane & 15;

    // bijective XCD chunk swizzle (nwg % 8 == 0 for all launches here),
    // then column-major decomposition -> each XCD works one B column panel.
    const int gx = gridDim.x, gy = gridDim.y;
    const int nwg = gx * gy;
    const int lin = blockIdx.y * gx + blockIdx.x;
    const int swz = (lin & 7) * (nwg >> 3) + (lin >> 3);
    const int colBlk = swz / gy;
    const int rowBlk = swz - colBlk * gy;
    const int rowBase = rowBlk * 256;
    const int colBase = colBlk * 256;

    f32x4 acc[8][4];
    #pragma unroll
    for (int i = 0; i < 8; ++i)
        #pragma unroll
        for (int j = 0; j < 4; ++j)
            acc[i][j] = (f32x4){0.f, 0.f, 0.f, 0.f};

    // staging: wave w covers tile rows [w*32, w*32+32), 4 rounds of 8 rows.
    // lane i -> row_local i>>3, LDS chunk i&7; global chunk = (i&7)^(row&7).
    const int srow   = lane >> 3;                 // 0..7
    const int gchunk = (lane & 7) ^ srow;
    const int scol   = gchunk * 8;
    const bf16_t* pA = A + (long)(rowBase + wave * 32 + srow) * LDA + scol;
    const bf16_t* pB = B + (long)(colBase + wave * 32 + srow) * LDB + scol;

    // fragment-read chunk selectors (unswizzled chunk ks*4+quad at row r,
    // stored at chunk (ks*4+quad)^(r&7); r&7 == l16&7 for all frag rows)
    const int cs0 = ((0 * 4 + quad) ^ (l16 & 7)) * 8;
    const int cs1 = ((1 * 4 + quad) ^ (l16 & 7)) * 8;

    constexpr int NT = K / 64;

    // prologue: stage K-tile 0 into buf 0 (8 global_load_lds / thread)
    #pragma unroll
    for (int j = 0; j < 4; ++j) {
        GLD16(pA + (long)(j * 8) * LDA, &smem[0][0][(wave * 32 + j * 8) * 64]);
        GLD16(pB + (long)(j * 8) * LDB, &smem[0][1][(wave * 32 + j * 8) * 64]);
    }
    pA += 64; pB += 64;

    #pragma unroll 1
    for (int t = 0; t < NT; ++t) {
        const int cur = t & 1;
        // tile-t staging landed (own loads) + visible to all (barrier).
        // These loads were issued 1.5-3k cy ago (spread over tile t-1) ->
        // this drain is near-free, unlike a just-issued-burst drain.
        asm volatile("s_waitcnt vmcnt(0)" ::: "memory");
        asm volatile("s_barrier" ::: "memory");
        SB();

        const bf16_t* Ab = &smem[cur][0][0];
        const bf16_t* Bb = &smem[cur][1][0];
        bf16_t* sA1 = &smem[cur ^ 1][0][0];
        bf16_t* sB1 = &smem[cur ^ 1][1][0];
        const bool stage = (t + 1 < NT);

        bf16x8 af0[4][2], af1[4][2], bq0[2][2], bq1[2][2];

        // ================= P1: q00 =================
        // reads kh0-group first -> compiler waits lgkmcnt(6) before kh0 MFMAs
        #pragma unroll
        for (int mi = 0; mi < 4; ++mi)
            af0[mi][0] = *(const bf16x8*)&Ab[(wm * 128 + mi * 16 + l16) * 64 + cs0];
        #pragma unroll
        for (int ni = 0; ni < 2; ++ni)
            bq0[ni][0] = *(const bf16x8*)&Bb[(wn * 64 + ni * 16 + l16) * 64 + cs0];
        SB();
        #pragma unroll
        for (int mi = 0; mi < 4; ++mi)
            af0[mi][1] = *(const bf16x8*)&Ab[(wm * 128 + mi * 16 + l16) * 64 + cs1];
        #pragma unroll
        for (int ni = 0; ni < 2; ++ni)
            bq0[ni][1] = *(const bf16x8*)&Bb[(wn * 64 + ni * 16 + l16) * 64 + cs1];
        SB();
        if (stage) {   // 4 GLD (pairs j=0,1)
            GLD16(pA + (long)(0 * 8) * LDA, sA1 + (wave * 32 + 0 * 8) * 64);
            GLD16(pB + (long)(0 * 8) * LDB, sB1 + (wave * 32 + 0 * 8) * 64);
            GLD16(pA + (long)(1 * 8) * LDA, sA1 + (wave * 32 + 1 * 8) * 64);
            GLD16(pB + (long)(1 * 8) * LDB, sB1 + (wave * 32 + 1 * 8) * 64);
        }
        SB();
        __builtin_amdgcn_s_setprio(1);
        #pragma unroll
        for (int mi = 0; mi < 4; ++mi)
            #pragma unroll
            for (int ni = 0; ni < 2; ++ni)
                acc[mi][ni] = __builtin_amdgcn_mfma_f32_16x16x32_bf16(
                    af0[mi][0], bq0[ni][0], acc[mi][ni], 0, 0, 0);
        SB();
        #pragma unroll
        for (int mi = 0; mi < 4; ++mi)
            #pragma unroll
            for (int ni = 0; ni < 2; ++ni)
                acc[mi][ni] = __builtin_amdgcn_mfma_f32_16x16x32_bf16(
                    af0[mi][1], bq0[ni][1], acc[mi][ni], 0, 0, 0);
        __builtin_amdgcn_s_setprio(0);
        SB();
        asm volatile("s_barrier" ::: "memory");
        SB();

        // ================= P2: q01 =================
        // bq1 first (this phase's operand), then af1 prefetch (stays in
        // flight under this phase's MFMA -> lgkmcnt(8) before q01)
        #pragma unroll
        for (int ni = 0; ni < 2; ++ni) {
            bq1[ni][0] = *(const bf16x8*)&Bb[(wn * 64 + 32 + ni * 16 + l16) * 64 + cs0];
            bq1[ni][1] = *(const bf16x8*)&Bb[(wn * 64 + 32 + ni * 16 + l16) * 64 + cs1];
        }
        SB();
        #pragma unroll
        for (int mi = 0; mi < 4; ++mi) {
            af1[mi][0] = *(const bf16x8*)&Ab[(wm * 128 + 64 + mi * 16 + l16) * 64 + cs0];
            af1[mi][1] = *(const bf16x8*)&Ab[(wm * 128 + 64 + mi * 16 + l16) * 64 + cs1];
        }
        SB();
        if (stage) {   // 2 GLD (pair j=2)
            GLD16(pA + (long)(2 * 8) * LDA, sA1 + (wave * 32 + 2 * 8) * 64);
            GLD16(pB + (long)(2 * 8) * LDB, sB1 + (wave * 32 + 2 * 8) * 64);
        }
        SB();
        __builtin_amdgcn_s_setprio(1);
        #pragma unroll
        for (int mi = 0; mi < 4; ++mi)
            #pragma unroll
            for (int ni = 0; ni < 2; ++ni) {
                acc[mi][2 + ni] = __builtin_amdgcn_mfma_f32_16x16x32_bf16(
                    af0[mi][0], bq1[ni][0], acc[mi][2 + ni], 0, 0, 0);
                acc[mi][2 + ni] = __builtin_amdgcn_mfma_f32_16x16x32_bf16(
                    af0[mi][1], bq1[ni][1], acc[mi][2 + ni], 0, 0, 0);
            }
        __builtin_amdgcn_s_setprio(0);
        SB();
        asm volatile("s_barrier" ::: "memory");
        SB();

        // ================= P3: q10 =================
        if (stage) {   // 2 GLD (pair j=3)
            GLD16(pA + (long)(3 * 8) * LDA, sA1 + (wave * 32 + 3 * 8) * 64);
            GLD16(pB + (long)(3 * 8) * LDB, sB1 + (wave * 32 + 3 * 8) * 64);
            pA += 64; pB += 64;
        }
        SB();
        __builtin_amdgcn_s_setprio(1);
        #pragma unroll
        for (int mi = 0; mi < 4; ++mi)
            #pragma unroll
            for (int ni = 0; ni < 2; ++ni) {
                acc[4 + mi][ni] = __builtin_amdgcn_mfma_f32_16x16x32_bf16(
                    af1[mi][0], bq0[ni][0], acc[4 + mi][ni], 0, 0, 0);
                acc[4 + mi][ni] = __builtin_amdgcn_mfma_f32_16x16x32_bf16(
                    af1[mi][1], bq0[ni][1], acc[4 + mi][ni], 0, 0, 0);
            }
        __builtin_amdgcn_s_setprio(0);
        SB();
        asm volatile("s_barrier" ::: "memory");
        SB();

        // ================= P4: q11 (no reads) =================
        __builtin_amdgcn_s_setprio(1);
        #pragma unroll
        for (int mi = 0; mi < 4; ++mi)
            #pragma unroll
            for (int ni = 0; ni < 2; ++ni) {
                acc[4 + mi][2 + ni] = __builtin_amdgcn_mfma_f32_16x16x32_bf16(
                    af1[mi][0], bq1[ni][0], acc[4 + mi][2 + ni], 0, 0, 0);
                acc[4 + mi][2 + ni] = __builtin_amdgcn_mfma_f32_16x16x32_bf16(
                    af1[mi][1], bq1[ni][1], acc[4 + mi][2 + ni], 0, 0, 0);
            }
        __builtin_amdgcn_s_setprio(0);
        SB();
        // next tile's top [vmcnt(0); s_barrier] is P4's trailing rendezvous
    }

    // epilogue: C/D layout col = lane&15, row = quad*4 + reg
    #pragma unroll
    for (int mi = 0; mi < 8; ++mi) {
        #pragma unroll
        for (int ni = 0; ni < 4; ++ni) {
            #pragma unroll
            for (int r = 0; r < 4; ++r) {
                const int row = rowBase + wm * 128 + mi * 16 + quad * 4 + r;
                const int col = colBase + wn * 64 + ni * 16 + l16;
                const long idx = (long)z * sC + (long)row * LDC + col;
                epi_store(MODE, Cg, bias, idx, col, acc[mi][ni][r], scale);
            }
        }
    }
}

// ---------------------------------------------------------------------------
// 128x128 tile kernel (R6 structure) -- kept for G2/G3 whose 256^2 grids
// would only fill 64-128 of the 256 CUs.
// ---------------------------------------------------------------------------
template<int MODE, int K, int LDA, int LDB, int LDC>
__global__ __launch_bounds__(256)
void gemm_bt(const bf16_t* __restrict__ Ag, const bf16_t* __restrict__ Bg,
             void* __restrict__ Cg, const float* __restrict__ bias,
             long sA, long sB, long sC, float scale)
{
    __shared__ alignas(16) bf16_t As[BM * BK];   // 16 KB
    __shared__ alignas(16) bf16_t Bs[BN * BK];   // 16 KB

    const int z = blockIdx.z;
    const bf16_t* A = Ag + (long)z * sA;
    const bf16_t* B = Bg + (long)z * sB;

    const int tid  = threadIdx.x;
    const int lane = tid & 63;
    const int wave = tid >> 6;
    const int wr   = (wave >> 1) * 64;   // wave row offset in 128x128 tile
    const int wc   = (wave & 1) * 64;    // wave col offset
    const int quad = lane >> 4;          // 0..3
    const int l16  = lane & 15;

    // XCD swizzle: column-major reinterpretation of the linear block ID
    const int bidLin = blockIdx.y * gridDim.x + blockIdx.x;
    const int colBlk = bidLin / gridDim.y;
    const int rowBlk = bidLin - colBlk * gridDim.y;
    const int rowBase = rowBlk * BM;
    const int colBase = colBlk * BN;

    f32x4 acc[4][4];
    #pragma unroll
    for (int i = 0; i < 4; ++i)
        #pragma unroll
        for (int j = 0; j < 4; ++j)
            acc[i][j] = (f32x4){0.f, 0.f, 0.f, 0.f};

    const int srow   = lane >> 3;                  // 0..7
    const int gchunk = (lane & 7) ^ srow;          // swizzled global chunk
    const int scol   = gchunk * 8;                 // element offset 0..56

    const bf16_t* pA = A + (long)(rowBase + wave * 32 + srow) * LDA + scol;
    const bf16_t* pB = B + (long)(colBase + wave * 32 + srow) * LDB + scol;
    bf16_t* lA = &As[(wave * 32) * BK];
    bf16_t* lB = &Bs[(wave * 32) * BK];

    const int csel0 = ((0 * 4 + quad) ^ (l16 & 7)) * 8;
    const int csel1 = ((1 * 4 + quad) ^ (l16 & 7)) * 8;

    #pragma unroll 1
    for (int k0 = 0; k0 < K; k0 += BK) {
        #pragma unroll
        for (int j = 0; j < 4; ++j) {
            GLD16(pA + (long)(j * 8) * LDA, lA + j * 8 * BK);
            GLD16(pB + (long)(j * 8) * LDB, lB + j * 8 * BK);
        }
        pA += BK; pB += BK;
        __syncthreads();   // drains vmcnt (global_load_lds)

        #pragma unroll
        for (int h = 0; h < 2; ++h) {
            const int cs = h ? csel1 : csel0;
            bf16x8 af[4], bfr[4];
            #pragma unroll
            for (int mi = 0; mi < 4; ++mi)
                af[mi] = *(const bf16x8*)(&As[(wr + mi * 16 + l16) * BK + cs]);
            #pragma unroll
            for (int ni = 0; ni < 4; ++ni)
                bfr[ni] = *(const bf16x8*)(&Bs[(wc + ni * 16 + l16) * BK + cs]);

            #pragma unroll
            for (int mi = 0; mi < 4; ++mi)
                #pragma unroll
                for (int ni = 0; ni < 4; ++ni)
                    acc[mi][ni] = __builtin_amdgcn_mfma_f32_16x16x32_bf16(
                        af[mi], bfr[ni], acc[mi][ni], 0, 0, 0);
        }
        __syncthreads();
    }

    #pragma unroll
    for (int mi = 0; mi < 4; ++mi) {
        #pragma unroll
        for (int ni = 0; ni < 4; ++ni) {
            #pragma unroll
            for (int r = 0; r < 4; ++r) {
                const int row = rowBase + wr + mi * 16 + quad * 4 + r;
                const int col = colBase + wc + ni * 16 + l16;
                const long idx = (long)z * sC + (long)row * LDC + col;
                epi_store(MODE, Cg, bias, idx, col, acc[mi][ni][r], scale);
            }
        }
    }
}

// fused prep: blocks [0,24576): cast input -> cat left half, cast memory -> memb,
//             copy memory -> out tail (float4 groups).
//             blocks [24576,32768): 32x32 transpose tiles for W1T/WmT/W2T/memT.
__global__ __launch_bounds__(256)
void prep_all(const float4* __restrict__ input, const float4* __restrict__ memory,
              const float* __restrict__ W_in1, const float* __restrict__ W_mem1,
              const float* __restrict__ W_in2,
              bf16_t* __restrict__ cat, bf16_t* __restrict__ memb,
              float4* __restrict__ outTail,
              bf16_t* __restrict__ W1T, bf16_t* __restrict__ WmT,
              bf16_t* __restrict__ W2T, bf16_t* __restrict__ memT)
{
    __shared__ float tile[32][33];
    const int bid = blockIdx.x;
    if (bid < 24576) {
        const long i = (long)bid * 256 + threadIdx.x;
        if (i < 4194304L) {               // input cast -> cat left half
            const float4 v = input[i];
            const long e = i << 2;
            const long row = e >> 10;
            const int  col = (int)(e & 1023);
            bf16_t* o = cat + row * 2048 + col;
            o[0] = __float2bfloat16(v.x);
            o[1] = __float2bfloat16(v.y);
            o[2] = __float2bfloat16(v.z);
            o[3] = __float2bfloat16(v.w);
        } else if (i < 5242880L) {        // memory cast (contiguous)
            const long j = i - 4194304L;
            const float4 v = memory[j];
            bf16_t* o = memb + (j << 2);
            o[0] = __float2bfloat16(v.x);
            o[1] = __float2bfloat16(v.y);
            o[2] = __float2bfloat16(v.z);
            o[3] = __float2bfloat16(v.w);
        } else {                          // memory passthrough -> out tail
            const long j = i - 5242880L;
            outTail[j] = memory[j];
        }
        return;
    }

    // transpose section: out[c][r] = bf16(in[r][c]), 32x32 tiles
    int local = bid - 24576;
    const float* in; bf16_t* out; int R, C, bx, by;
    if (local < 1024)      { in = W_in1;  out = W1T; R = 1024; C = 1024;
                             bx = local & 31; by = local >> 5; }
    else if (local < 2048) { local -= 1024; in = W_mem1; out = WmT; R = 1024; C = 1024;
                             bx = local & 31; by = local >> 5; }
    else if (local < 4096) { local -= 2048; in = W_in2;  out = W2T; R = 2048; C = 1024;
                             bx = local & 31; by = local >> 5; }
    else                   { local -= 4096;
                             const int zz = local >> 9;          // 0..7
                             const int r  = local & 511;
                             bx = r & 31; by = r >> 5;           // by 0..15
                             in  = (const float*)memory + (long)zz * 524288;
                             out = memT + (long)zz * 524288;
                             R = 512; C = 1024; }

    const int x = threadIdx.x & 31, y = threadIdx.x >> 5;   // y in 0..7
    const int c0 = bx * 32, r0 = by * 32;
    #pragma unroll
    for (int i = 0; i < 32; i += 8)
        tile[y + i][x] = in[(long)(r0 + y + i) * C + c0 + x];
    __syncthreads();
    #pragma unroll
    for (int i = 0; i < 32; i += 8)
        out[(long)(c0 + y + i) * R + r0 + x] = __float2bfloat16(tile[x][y + i]);
}

// one wave per row of 512; att fp32 in, compact bf16 weights out (row stride 512).
__global__ __launch_bounds__(256)
void softmax_rows(const float* __restrict__ att, const int* __restrict__ mask,
                  bf16_t* __restrict__ wAtt)
{
    const int lane = threadIdx.x & 63;
    const long row = (long)blockIdx.x * 4 + (threadIdx.x >> 6);
    const int n = (int)(row >> 11);          // 2048 rows per batch
    const float* base = att + row * 512;
    const int* mrow = mask + n * 512;

    float v[8];
    #pragma unroll
    for (int j = 0; j < 8; ++j) {
        const int idx = j * 64 + lane;
        const float x = base[idx];
        v[j] = mrow[idx] ? x : -1e30f;
    }
    float mx = v[0];
    #pragma unroll
    for (int j = 1; j < 8; ++j) mx = fmaxf(mx, v[j]);
    #pragma unroll
    for (int off = 32; off >= 1; off >>= 1) mx = fmaxf(mx, __shfl_xor(mx, off, 64));
    float s = 0.f;
    #pragma unroll
    for (int j = 0; j < 8; ++j) { v[j] = __expf(v[j] - mx); s += v[j]; }
    #pragma unroll
    for (int off = 32; off >= 1; off >>= 1) s += __shfl_xor(s, off, 64);
    const float inv = 1.0f / s;

    bf16_t* w = wAtt + row * 512;
    #pragma unroll
    for (int j = 0; j < 8; ++j)
        w[j * 64 + lane] = __float2bfloat16(v[j] * inv);
}

extern "C" void kernel_launch(void* const* d_in, const int* in_sizes, int n_in,
                              void* d_out, int out_size, void* d_ws, size_t ws_size,
                              hipStream_t stream)
{
    const float* input  = (const float*)d_in[0];   // 8 x 2048 x 1024
    const float* memory = (const float*)d_in[1];   // 8 x 512 x 1024
    const int*   mask   = (const int*)  d_in[2];   // 8 x 512
    const float* W_in1  = (const float*)d_in[3];   // 1024 x 1024
    const float* b_in1  = (const float*)d_in[4];
    const float* W_mem1 = (const float*)d_in[5];   // 1024 x 1024
    const float* b_mem1 = (const float*)d_in[6];
    const float* W_in2  = (const float*)d_in[7];   // 2048 x 1024
    const float* b_in2  = (const float*)d_in[8];
    float* out = (float*)d_out;                    // 16777216 gated + 4194304 memory

    char* ws = (char*)d_ws;
    bf16_t* cat         = (bf16_t*)(ws);                 // 16384 x 2048   (67108864 B)
    bf16_t* input_dot   = (bf16_t*)(ws + 67108864);      // 16384 x 1024   (33554432 B)
    bf16_t* memory_dot  = (bf16_t*)(ws + 100663296);     //  4096 x 1024   ( 8388608 B)
    bf16_t* memory_bf16 = (bf16_t*)(ws + 109051904);     //  4096 x 1024   ( 8388608 B)
    bf16_t* memT        = (bf16_t*)(ws + 117440512);     // 8 x 1024 x 512 ( 8388608 B)
    bf16_t* W1T         = (bf16_t*)(ws + 125829120);     // 1024 x 1024    ( 2097152 B)
    bf16_t* WmT         = (bf16_t*)(ws + 127926272);     // 1024 x 1024    ( 2097152 B)
    bf16_t* W2T         = (bf16_t*)(ws + 130023424);     // 1024 x 2048    ( 4194304 B)
    float*  att         = (float*)(ws + 134217728);      // 8 x 2048 x 512 (33554432 B) -> end 167772160
    bf16_t* wAtt        = input_dot;   // reclaimed after G3: compact bf16 softmax weights

    // fused prep (casts + passthrough + all transposes)
    prep_all<<<32768, 256, 0, stream>>>((const float4*)input, (const float4*)memory,
                                        W_in1, W_mem1, W_in2,
                                        cat, memory_bf16, (float4*)(out + 16777216L),
                                        W1T, WmT, W2T, memT);

    // G1: input_dot = relu(input @ W_in1 + b_in1)   [256^2, 256 blocks]
    gemm256<EPI_RELU_BIAS_BF16, 1024, 2048, 1024, 1024><<<dim3(4, 64, 1), 512, 0, stream>>>(
        cat, W1T, input_dot, b_in1, 0, 0, 0, 1.0f);
    // G2: memory_dot = relu(memory @ W_mem1 + b_mem1)   [128^2, 256 blocks]
    gemm_bt<EPI_RELU_BIAS_BF16, 1024, 1024, 1024, 1024><<<dim3(8, 32, 1), 256, 0, stream>>>(
        memory_bf16, WmT, memory_dot, b_mem1, 0, 0, 0, 1.0f);
    // G3: att = input_dot @ memory_dot^T / 32   (batched)   [128^2, 512 blocks]
    gemm_bt<EPI_SCALE_F32, 1024, 1024, 1024, 512><<<dim3(4, 16, 8), 256, 0, stream>>>(
        input_dot, memory_dot, att, nullptr,
        2048L * 1024, 512L * 1024, 2048L * 512, 0.03125f);
    // softmax: fp32 att -> compact bf16 wAtt (input_dot buffer is dead after G3)
    softmax_rows<<<4096, 256, 0, stream>>>(att, mask, wAtt);
    // G4: output_one = wAtt @ memT^T -> cat[:, 1024:2048]   [256^2, 256 blocks]
    gemm256<EPI_BF16, 512, 512, 512, 2048><<<dim3(4, 8, 8), 512, 0, stream>>>(
        wAtt, memT, cat + 1024, nullptr,
        2048L * 512, 1024L * 512, 2048L * 2048, 1.0f);
    // G5: out = sigmoid(pre) * tanh(pre), pre = cat @ W_in2 + b_in2   [256^2]
    gemm256<EPI_GATE_BIAS_F32, 2048, 2048, 2048, 1024><<<dim3(4, 64, 1), 512, 0, stream>>>(
        cat, W2T, out, b_in2, 0, 0, 0, 1.0f);
}